// Round 8
// baseline (292.528 us; speedup 1.0000x reference)
//
#include <hip/hip_runtime.h>
#include <stdint.h>

#define N_PIX 4096
#define NB 8

typedef __attribute__((ext_vector_type(8))) short short8;
typedef __attribute__((ext_vector_type(4))) float f32x4;
typedef __attribute__((ext_vector_type(2))) uint32_t u32x2;

#define SCL 0.18033688011112042f   // log2(e)/8
#define LOG2E 1.4426950408889634f

__device__ __forceinline__ short f2bf(float x){
  union { float f; uint32_t u; } a; a.f = x;
  uint32_t r = a.u + 0x7FFFu + ((a.u >> 16) & 1u);
  return (short)(r >> 16);
}
__device__ __forceinline__ float bf2f(short h){
  union { uint32_t u; float f; } a; a.u = ((uint32_t)(uint16_t)h) << 16; return a.f;
}
__device__ __forceinline__ uint32_t cvtpk(float lo, float hi){
  uint32_t r;
  asm("v_cvt_pk_bf16_f32 %0, %1, %2" : "=v"(r) : "v"(lo), "v"(hi));
  return r;
}
__device__ __forceinline__ float fexp2(float x){ return __builtin_amdgcn_exp2f(x); }
__device__ __forceinline__ float wredSum(float v){
  #pragma unroll
  for (int m = 1; m < 64; m <<= 1) v += __shfl_xor(v, m);
  return v;
}
// padded LDS index maps (pad 4 dwords per 64 dwords; 2*pd(d) == ps(2d))
__device__ __forceinline__ int pd(int d){ return d + ((d >> 6) << 2); }
__device__ __forceinline__ int ps(int s){ return s + ((s >> 7) << 3); }

// ---------------- K0: per-(b,c) spatial mean of x ----------------
__global__ __launch_bounds__(256) void k_xmean(const float* __restrict__ x, float* __restrict__ xm){
  int b = blockIdx.x & 7, c = blockIdx.x >> 3;
  int row = b*64 + c;
  int tid = threadIdx.x;
  const float* xr = x + (size_t)row * N_PIX;
  float s = 0.f;
  #pragma unroll
  for (int i = 0; i < 16; i++) s += xr[tid + 256*i];
  s = wredSum(s);
  __shared__ float red[4];
  if ((tid & 63) == 0) red[tid >> 6] = s;
  __syncthreads();
  if (tid == 0) xm[row] = (red[0]+red[1]+red[2]+red[3]) * (1.0f / N_PIX);
}

// ---------------- K1: QKV GEMM + whitening + unary logits + fragment layouts ----------------
// Q : [B][N][64] bf16 (row layout), whitened & pre-scaled by log2(e)/8
// Kf: [B][N/16][2 chain][64 lane][8] bf16 — QK A-fragments
// Vf: [B][N/32][4 f][64 lane][8] bf16  — PV A-fragments (V^T), pi key order
// u : [B][N] f32
// All three outputs staged through padded LDS -> coalesced 16B stores.
__global__ __launch_bounds__(256) void k_qkv(
    const float* __restrict__ x,
    const float* __restrict__ wq, const float* __restrict__ bq,
    const float* __restrict__ wk, const float* __restrict__ bk,
    const float* __restrict__ wv, const float* __restrict__ bv,
    const float* __restrict__ xm,
    short* __restrict__ Q, short* __restrict__ Kf, short* __restrict__ Vf,
    float* __restrict__ u)
{
  int blk = blockIdx.x;
  int b  = blk & 7;                  // XCD affinity: batch b -> XCD b
  int n0 = (blk >> 3) * 128;
  int tid = threadIdx.x;
  int w = tid >> 6, l = tid & 63, lr = l & 15, lg = l >> 4;
  const float* xb = x + (size_t)b * 64 * N_PIX;

  // qm/km via LDS matvec (folds old k_means)
  __shared__ float qms[64], kms[64];
  __shared__ short stage[4][2176];   // per-wave padded staging (4352B each)
  if (tid < 64){
    float sq = 0.f, sk = 0.f;
    #pragma unroll 8
    for (int cc = 0; cc < 64; cc++){
      float xv = xm[b*64 + cc];
      sq += wq[tid*64 + cc] * xv;
      sk += wk[tid*64 + cc] * xv;
    }
    qms[tid] = sq + bq[tid];
    kms[tid] = sk + bk[tid];
  }
  __syncthreads();

  short* stageW = stage[w];
  uint32_t* sd = (uint32_t*)stageW;

  int ncol[2];
  ncol[0] = n0 + w*32 + lr;
  ncol[1] = ncol[0] + 16;

  // B-fragments from x (shared across the 3 matrices)
  short8 bx[2][2];
  #pragma unroll
  for (int tj = 0; tj < 2; tj++){
    #pragma unroll
    for (int kc = 0; kc < 2; kc++){
      short8 t;
      #pragma unroll
      for (int j = 0; j < 8; j++){
        int cp = kc*32 + lg*8 + j;
        t[j] = f2bf(xb[(size_t)cp * N_PIX + ncol[tj]]);
      }
      bx[tj][kc] = t;
    }
  }

  float qmv[4][4];
  #pragma unroll
  for (int ti = 0; ti < 4; ti++)
    #pragma unroll
    for (int r = 0; r < 4; r++)
      qmv[ti][r] = qms[ti*16 + lg*4 + r];

  size_t wbase = (size_t)(n0 + w*32) * 64;   // contiguous 2048-short span per wave
  short* Qb  = Q  + (size_t)b * N_PIX * 64;
  short* Kfb = Kf + (size_t)b * N_PIX * 64;
  short* Vfb = Vf + (size_t)b * N_PIX * 64;
  const f32x4 z4 = {0.f, 0.f, 0.f, 0.f};

  // ---------- Q ----------
  {
    short8 aw[4][2];
    #pragma unroll
    for (int ti = 0; ti < 4; ti++)
      #pragma unroll
      for (int kc = 0; kc < 2; kc++){
        const float* wr = wq + (ti*16 + lr)*64 + kc*32 + lg*8;
        short8 t;
        #pragma unroll
        for (int j = 0; j < 8; j++) t[j] = f2bf(wr[j]);
        aw[ti][kc] = t;
      }
    f32x4 acc[4][2];
    #pragma unroll
    for (int ti = 0; ti < 4; ti++)
      #pragma unroll
      for (int tj = 0; tj < 2; tj++){
        acc[ti][tj] = z4;
        #pragma unroll
        for (int kc = 0; kc < 2; kc++)
          acc[ti][tj] = __builtin_amdgcn_mfma_f32_16x16x32_bf16(aw[ti][kc], bx[tj][kc], acc[ti][tj], 0, 0, 0);
      }
    #pragma unroll
    for (int ti = 0; ti < 4; ti++)
      #pragma unroll
      for (int tj = 0; tj < 2; tj++){
        float a0 = bq[ti*16 + lg*4 + 0] - qmv[ti][0];
        float a1 = bq[ti*16 + lg*4 + 1] - qmv[ti][1];
        float a2 = bq[ti*16 + lg*4 + 2] - qmv[ti][2];
        float a3 = bq[ti*16 + lg*4 + 3] - qmv[ti][3];
        float v0 = (acc[ti][tj][0] + a0) * SCL;
        float v1 = (acc[ti][tj][1] + a1) * SCL;
        float v2 = (acc[ti][tj][2] + a2) * SCL;
        float v3 = (acc[ti][tj][3] + a3) * SCL;
        int loc = tj*16 + lr;
        int qd = loc*32 + ti*8 + lg*2;
        sd[pd(qd)]     = cvtpk(v0, v1);
        sd[pd(qd + 1)] = cvtpk(v2, v3);
      }
    #pragma unroll
    for (int c2 = 0; c2 < 4; c2++){
      int s = c2*512 + l*8;
      short8 v = *(const short8*)(stageW + ps(s));
      *(short8*)(Qb + wbase + s) = v;
    }
  }

  // ---------- K -> Kf fragments (+ unary logits) ----------
  {
    short8 aw[4][2];
    #pragma unroll
    for (int ti = 0; ti < 4; ti++)
      #pragma unroll
      for (int kc = 0; kc < 2; kc++){
        const float* wr = wk + (ti*16 + lr)*64 + kc*32 + lg*8;
        short8 t;
        #pragma unroll
        for (int j = 0; j < 8; j++) t[j] = f2bf(wr[j]);
        aw[ti][kc] = t;
      }
    f32x4 acc[4][2];
    #pragma unroll
    for (int ti = 0; ti < 4; ti++)
      #pragma unroll
      for (int tj = 0; tj < 2; tj++){
        acc[ti][tj] = z4;
        #pragma unroll
        for (int kc = 0; kc < 2; kc++)
          acc[ti][tj] = __builtin_amdgcn_mfma_f32_16x16x32_bf16(aw[ti][kc], bx[tj][kc], acc[ti][tj], 0, 0, 0);
      }
    float up[2] = {0.f, 0.f};
    #pragma unroll
    for (int ti = 0; ti < 4; ti++)
      #pragma unroll
      for (int tj = 0; tj < 2; tj++){
        float v0 = acc[ti][tj][0] + bk[ti*16 + lg*4 + 0] - kms[ti*16 + lg*4 + 0];
        float v1 = acc[ti][tj][1] + bk[ti*16 + lg*4 + 1] - kms[ti*16 + lg*4 + 1];
        float v2 = acc[ti][tj][2] + bk[ti*16 + lg*4 + 2] - kms[ti*16 + lg*4 + 2];
        float v3 = acc[ti][tj][3] + bk[ti*16 + lg*4 + 3] - kms[ti*16 + lg*4 + 3];
        up[tj] += qmv[ti][0]*v0 + qmv[ti][1]*v1 + qmv[ti][2]*v2 + qmv[ti][3]*v3;
        // local fragment dword index within this wave's 1024-dword Kf span
        int kd = tj*512 + (ti>>1)*256 + (lr + 16*(2*(ti&1) + (lg>>1)))*4 + (lg&1)*2;
        sd[pd(kd)]     = cvtpk(v0, v1);
        sd[pd(kd + 1)] = cvtpk(v2, v3);
      }
    #pragma unroll
    for (int c2 = 0; c2 < 4; c2++){
      int s = c2*512 + l*8;
      short8 v = *(const short8*)(stageW + ps(s));
      *(short8*)(Kfb + wbase + s) = v;
    }
    #pragma unroll
    for (int tj = 0; tj < 2; tj++){
      float s = up[tj];
      s += __shfl_xor(s, 16);
      s += __shfl_xor(s, 32);
      if (lg == 0) u[(size_t)b*N_PIX + ncol[tj]] = s;
    }
  }

  // ---------- V -> Vf fragments (V^T, pi key order) ----------
  {
    short8 aw[4][2];
    #pragma unroll
    for (int ti = 0; ti < 4; ti++)
      #pragma unroll
      for (int kc = 0; kc < 2; kc++){
        const float* wr = wv + (ti*16 + lr)*64 + kc*32 + lg*8;
        short8 t;
        #pragma unroll
        for (int j = 0; j < 8; j++) t[j] = f2bf(wr[j]);
        aw[ti][kc] = t;
      }
    f32x4 acc[4][2];
    #pragma unroll
    for (int ti = 0; ti < 4; ti++)
      #pragma unroll
      for (int tj = 0; tj < 2; tj++){
        acc[ti][tj] = z4;
        #pragma unroll
        for (int kc = 0; kc < 2; kc++)
          acc[ti][tj] = __builtin_amdgcn_mfma_f32_16x16x32_bf16(aw[ti][kc], bx[tj][kc], acc[ti][tj], 0, 0, 0);
      }
    #pragma unroll
    for (int ti = 0; ti < 4; ti++)
      #pragma unroll
      for (int tj = 0; tj < 2; tj++){
        #pragma unroll
        for (int r = 0; r < 4; r++){
          float v = acc[ti][tj][r] + bv[ti*16 + lg*4 + r];
          int vs0 = ti*512 + ((lr >> 2)*16 + lg*4 + r)*8 + (lr & 3) + 4*tj;
          stageW[ps(vs0)] = f2bf(v);
        }
      }
    #pragma unroll
    for (int c2 = 0; c2 < 4; c2++){
      int s = c2*512 + l*8;
      short8 v = *(const short8*)(stageW + ps(s));
      *(short8*)(Vfb + wbase + s) = v;
    }
  }
}

// ---------------- K2: unary softmax + out_unary (no max pass; u bounded) ----------------
__global__ __launch_bounds__(256) void k_unary(const float* __restrict__ u, const short* __restrict__ Vf,
                                               float* __restrict__ ou){
  int b = blockIdx.x & 7, c = blockIdx.x >> 3;
  int tid = threadIdx.x, w = tid >> 6, l = tid & 63;
  const float* ub = u + (size_t)b * N_PIX;
  const short* Vfb = Vf + (size_t)b * N_PIX * 64;
  int f = c >> 4, c15 = c & 15;
  int g = tid >> 1, h = tid & 1;   // thread covers key-group g, lane-slots 2h,2h+1
  float ps_ = 0.f, vs = 0.f;
  #pragma unroll
  for (int si = 0; si < 2; si++){
    int s = 2*h + si;
    const short8 v = *(const short8*)(Vfb + g*2048 + f*512 + (s*16 + c15)*8);
    #pragma unroll
    for (int j = 0; j < 8; j++){
      int kk = (j < 4) ? (4*s + j) : (16 + 4*s + (j - 4));
      int m = g*32 + kk;
      float p = fexp2(ub[m] * LOG2E);
      ps_ += p;
      vs += p * bf2f(v[j]);
    }
  }
  ps_ = wredSum(ps_); vs = wredSum(vs);
  __shared__ float r1[4], r2[4];
  if (l == 0){ r1[w] = ps_; r2[w] = vs; }
  __syncthreads();
  if (tid == 0) ou[b*64 + c] = (r2[0]+r2[1]+r2[2]+r2[3]) / (r1[0]+r1[1]+r1[2]+r1[3]);
}

// ---------------- K3: flash attention + epilogue ----------------
// In-register main loop (swapped QK, cvt_pk P->B-frag, pi-ordered Vf) with
// 2-deep named-register prefetch of K/V fragments (unroll-2, A/B sets).
#define LOADF(S, kb) do {                                             \
    const short* kp_ = Kfb + (size_t)(kb)*64 + l*8;                   \
    ak0##S = *(const short8*)(kp_);                                   \
    ak1##S = *(const short8*)(kp_ + 512);                             \
    ak2##S = *(const short8*)(kp_ + 1024);                            \
    ak3##S = *(const short8*)(kp_ + 1536);                            \
    const short* vp_ = Vfb + (size_t)(kb)*64 + l*8;                   \
    vf0##S = *(const short8*)(vp_);                                   \
    vf1##S = *(const short8*)(vp_ + 512);                             \
    vf2##S = *(const short8*)(vp_ + 1024);                            \
    vf3##S = *(const short8*)(vp_ + 1536);                            \
  } while(0)

#define COMPUTE(S) do {                                               \
    _Pragma("unroll")                                                 \
    for (int qt = 0; qt < 4; qt++){                                   \
      f32x4 s0 = __builtin_amdgcn_mfma_f32_16x16x32_bf16(ak0##S, bq[qt][0], z4, 0, 0, 0); \
      s0 = __builtin_amdgcn_mfma_f32_16x16x32_bf16(ak1##S, bq[qt][1], s0, 0, 0, 0); \
      f32x4 s1 = __builtin_amdgcn_mfma_f32_16x16x32_bf16(ak2##S, bq[qt][0], z4, 0, 0, 0); \
      s1 = __builtin_amdgcn_mfma_f32_16x16x32_bf16(ak3##S, bq[qt][1], s1, 0, 0, 0); \
      float p00 = fexp2(s0[0]), p01 = fexp2(s0[1]), p02 = fexp2(s0[2]), p03 = fexp2(s0[3]); \
      float p10 = fexp2(s1[0]), p11 = fexp2(s1[1]), p12 = fexp2(s1[2]), p13 = fexp2(s1[3]); \
      rs[qt] += ((p00 + p01) + (p02 + p03)) + ((p10 + p11) + (p12 + p13)); \
      union { short8 s; uint32_t u[4]; } pb;                          \
      pb.u[0] = cvtpk(p00, p01);                                      \
      pb.u[1] = cvtpk(p02, p03);                                      \
      pb.u[2] = cvtpk(p10, p11);                                      \
      pb.u[3] = cvtpk(p12, p13);                                      \
      acc[qt][0] = __builtin_amdgcn_mfma_f32_16x16x32_bf16(vf0##S, pb.s, acc[qt][0], 0, 0, 0); \
      acc[qt][1] = __builtin_amdgcn_mfma_f32_16x16x32_bf16(vf1##S, pb.s, acc[qt][1], 0, 0, 0); \
      acc[qt][2] = __builtin_amdgcn_mfma_f32_16x16x32_bf16(vf2##S, pb.s, acc[qt][2], 0, 0, 0); \
      acc[qt][3] = __builtin_amdgcn_mfma_f32_16x16x32_bf16(vf3##S, pb.s, acc[qt][3], 0, 0, 0); \
    }                                                                 \
  } while(0)

__global__ __launch_bounds__(512, 4) void k_attn(
    const short* __restrict__ Q, const short* __restrict__ Kf, const short* __restrict__ Vf,
    const float* __restrict__ ou, const float* __restrict__ x, float* __restrict__ out)
{
  int blk = blockIdx.x;
  int b  = blk & 7;                 // XCD-affinity: batch b -> XCD b
  int q0 = (blk >> 3) << 6;
  int tid = threadIdx.x;
  int w = tid >> 6, l = tid & 63, lr = l & 15, lg = l >> 4;

  __shared__ short Opart[8][64][66];   // [wave][q][c] bf16 partials (epilogue only)
  __shared__ float lW[8][64];

  const short* Qb  = Q  + (size_t)b * N_PIX * 64;
  const short* Kfb = Kf + (size_t)b * N_PIX * 64;
  const short* Vfb = Vf + (size_t)b * N_PIX * 64;

  short8 bq[4][2];
  #pragma unroll
  for (int qt = 0; qt < 4; qt++)
    #pragma unroll
    for (int kc = 0; kc < 2; kc++)
      bq[qt][kc] = *(const short8*)(Qb + (size_t)(q0 + qt*16 + lr)*64 + kc*32 + lg*8);

  f32x4 acc[4][4];
  float rs[4];
  const f32x4 z4 = {0.f, 0.f, 0.f, 0.f};
  #pragma unroll
  for (int qt = 0; qt < 4; qt++){
    rs[qt] = 0.f;
    #pragma unroll
    for (int f = 0; f < 4; f++) acc[qt][f] = z4;
  }

  int kbase = w << 9;   // each of 8 waves owns 512 keys
  short8 ak0A, ak1A, ak2A, ak3A, vf0A, vf1A, vf2A, vf3A;
  short8 ak0B, ak1B, ak2B, ak3B, vf0B, vf1B, vf2B, vf3B;

  LOADF(A, kbase);
  for (int it = 0; it < 16; it += 2){
    LOADF(B, kbase + ((((it + 1) & 15)) << 5));
    COMPUTE(A);
    LOADF(A, kbase + ((((it + 2) & 15)) << 5));   // wraps to dead load on tail
    COMPUTE(B);
  }

  #pragma unroll
  for (int qt = 0; qt < 4; qt++){
    float v = rs[qt];
    v += __shfl_xor(v, 16);
    v += __shfl_xor(v, 32);
    rs[qt] = v;
  }

  if (lg == 0){
    #pragma unroll
    for (int qt = 0; qt < 4; qt++)
      lW[w][qt*16 + lr] = rs[qt];
  }
  // O^T deposit: acc[qt][f][r] = O^T[c = f*16+lg*4+r][q = qt*16+lr]
  #pragma unroll
  for (int qt = 0; qt < 4; qt++)
    #pragma unroll
    for (int f = 0; f < 4; f++)
      #pragma unroll
      for (int r = 0; r < 4; r++)
        Opart[w][qt*16 + lr][f*16 + lg*4 + r] = f2bf(acc[qt][f][r]);
  __syncthreads();

  const float* xb = x + (size_t)b * 64 * N_PIX;
  float* ob = out + (size_t)b * 64 * N_PIX;
  const float* oub = ou + b*64;
  #pragma unroll
  for (int i = 0; i < 8; i++){
    int idx = i*512 + tid;
    int c = idx >> 6, q = idx & 63;
    float os = 0.f, lt = 0.f;
    #pragma unroll
    for (int ww = 0; ww < 8; ww++){
      os += bf2f(Opart[ww][q][c]);
      lt += lW[ww][q];
    }
    size_t gi = (size_t)c * N_PIX + q0 + q;
    ob[gi] = xb[gi] + os / lt + oub[c];
  }
}

extern "C" void kernel_launch(void* const* d_in, const int* in_sizes, int n_in,
                              void* d_out, int out_size, void* d_ws, size_t ws_size,
                              hipStream_t stream)
{
  (void)in_sizes; (void)n_in; (void)out_size; (void)ws_size;
  const float* x  = (const float*)d_in[0];
  const float* wq = (const float*)d_in[1];
  const float* bq = (const float*)d_in[2];
  const float* wk = (const float*)d_in[3];
  const float* bk = (const float*)d_in[4];
  const float* wv = (const float*)d_in[5];
  const float* bv = (const float*)d_in[6];
  float* out = (float*)d_out;

  char* ws = (char*)d_ws;
  short* Q  = (short*)(ws);                 // 4 MiB
  short* Kf = (short*)(ws + 4194304);       // 4 MiB (fragment layout)
  short* Vf = (short*)(ws + 8388608);       // 4 MiB (V^T fragment layout, pi order)
  float* u  = (float*)(ws + 12582912);      // 128 KiB
  float* xm = (float*)(ws + 12713984);
  float* ou = (float*)(ws + 12716032);

  k_xmean<<<dim3(512), dim3(256), 0, stream>>>(x, xm);
  k_qkv<<<dim3(256), dim3(256), 0, stream>>>(x, wq, bq, wk, bk, wv, bv, xm, Q, Kf, Vf, u);
  k_unary<<<dim3(512), dim3(256), 0, stream>>>(u, Vf, ou);
  k_attn<<<dim3(512), dim3(512), 0, stream>>>(Q, Kf, Vf, ou, x, out);
}

// Round 9
// 64.653 us; speedup vs baseline: 4.5246x; 4.5246x over previous
//
#include <hip/hip_runtime.h>
#include <stdint.h>

#define N_PIX 4096
#define NB 8

typedef __attribute__((ext_vector_type(8))) short short8;
typedef __attribute__((ext_vector_type(4))) float f32x4;
typedef __attribute__((ext_vector_type(2))) uint32_t u32x2;

#define SCL 0.18033688011112042f   // log2(e)/8
#define LOG2E 1.4426950408889634f

__device__ __forceinline__ short f2bf(float x){
  union { float f; uint32_t u; } a; a.f = x;
  uint32_t r = a.u + 0x7FFFu + ((a.u >> 16) & 1u);
  return (short)(r >> 16);
}
__device__ __forceinline__ float bf2f(short h){
  union { uint32_t u; float f; } a; a.u = ((uint32_t)(uint16_t)h) << 16; return a.f;
}
__device__ __forceinline__ uint32_t cvtpk(float lo, float hi){
  uint32_t r;
  asm("v_cvt_pk_bf16_f32 %0, %1, %2" : "=v"(r) : "v"(lo), "v"(hi));
  return r;
}
__device__ __forceinline__ float fexp2(float x){ return __builtin_amdgcn_exp2f(x); }
__device__ __forceinline__ float wredSum(float v){
  #pragma unroll
  for (int m = 1; m < 64; m <<= 1) v += __shfl_xor(v, m);
  return v;
}
// padded LDS index maps (pad 4 dwords per 64 dwords; 2*pd(d) == ps(2d))
__device__ __forceinline__ int pd(int d){ return d + ((d >> 6) << 2); }
__device__ __forceinline__ int ps(int s){ return s + ((s >> 7) << 3); }

// ---------------- K0: per-(b,c) spatial mean of x ----------------
__global__ __launch_bounds__(256) void k_xmean(const float* __restrict__ x, float* __restrict__ xm){
  int b = blockIdx.x & 7, c = blockIdx.x >> 3;
  int row = b*64 + c;
  int tid = threadIdx.x;
  const float* xr = x + (size_t)row * N_PIX;
  float s = 0.f;
  #pragma unroll
  for (int i = 0; i < 16; i++) s += xr[tid + 256*i];
  s = wredSum(s);
  __shared__ float red[4];
  if ((tid & 63) == 0) red[tid >> 6] = s;
  __syncthreads();
  if (tid == 0) xm[row] = (red[0]+red[1]+red[2]+red[3]) * (1.0f / N_PIX);
}

// ---------------- K1: QKV GEMM + whitening + unary logits + fragment layouts ----------------
// Q : [B][N][64] bf16 (row layout), whitened & pre-scaled by log2(e)/8
// Kf: [B][N/16][2 chain][64 lane][8] bf16 — QK A-fragments
// Vf: [B][N/32][4 f][64 lane][8] bf16  — PV A-fragments (V^T), pi key order
// u : [B][N] f32
// All three outputs staged through padded LDS -> coalesced 16B stores.
__global__ __launch_bounds__(256) void k_qkv(
    const float* __restrict__ x,
    const float* __restrict__ wq, const float* __restrict__ bq,
    const float* __restrict__ wk, const float* __restrict__ bk,
    const float* __restrict__ wv, const float* __restrict__ bv,
    const float* __restrict__ xm,
    short* __restrict__ Q, short* __restrict__ Kf, short* __restrict__ Vf,
    float* __restrict__ u)
{
  int blk = blockIdx.x;
  int b  = blk & 7;                  // XCD affinity: batch b -> XCD b
  int n0 = (blk >> 3) * 128;
  int tid = threadIdx.x;
  int w = tid >> 6, l = tid & 63, lr = l & 15, lg = l >> 4;
  const float* xb = x + (size_t)b * 64 * N_PIX;

  // qm/km via LDS matvec (folds old k_means)
  __shared__ float qms[64], kms[64];
  __shared__ short stage[4][2176];   // per-wave padded staging (4352B each)
  if (tid < 64){
    float sq = 0.f, sk = 0.f;
    #pragma unroll 8
    for (int cc = 0; cc < 64; cc++){
      float xv = xm[b*64 + cc];
      sq += wq[tid*64 + cc] * xv;
      sk += wk[tid*64 + cc] * xv;
    }
    qms[tid] = sq + bq[tid];
    kms[tid] = sk + bk[tid];
  }
  __syncthreads();

  short* stageW = stage[w];
  uint32_t* sd = (uint32_t*)stageW;

  int ncol[2];
  ncol[0] = n0 + w*32 + lr;
  ncol[1] = ncol[0] + 16;

  // B-fragments from x (shared across the 3 matrices)
  short8 bx[2][2];
  #pragma unroll
  for (int tj = 0; tj < 2; tj++){
    #pragma unroll
    for (int kc = 0; kc < 2; kc++){
      short8 t;
      #pragma unroll
      for (int j = 0; j < 8; j++){
        int cp = kc*32 + lg*8 + j;
        t[j] = f2bf(xb[(size_t)cp * N_PIX + ncol[tj]]);
      }
      bx[tj][kc] = t;
    }
  }

  float qmv[4][4];
  #pragma unroll
  for (int ti = 0; ti < 4; ti++)
    #pragma unroll
    for (int r = 0; r < 4; r++)
      qmv[ti][r] = qms[ti*16 + lg*4 + r];

  size_t wbase = (size_t)(n0 + w*32) * 64;   // contiguous 2048-short span per wave
  short* Qb  = Q  + (size_t)b * N_PIX * 64;
  short* Kfb = Kf + (size_t)b * N_PIX * 64;
  short* Vfb = Vf + (size_t)b * N_PIX * 64;
  const f32x4 z4 = {0.f, 0.f, 0.f, 0.f};

  // ---------- Q ----------
  {
    short8 aw[4][2];
    #pragma unroll
    for (int ti = 0; ti < 4; ti++)
      #pragma unroll
      for (int kc = 0; kc < 2; kc++){
        const float* wr = wq + (ti*16 + lr)*64 + kc*32 + lg*8;
        short8 t;
        #pragma unroll
        for (int j = 0; j < 8; j++) t[j] = f2bf(wr[j]);
        aw[ti][kc] = t;
      }
    f32x4 acc[4][2];
    #pragma unroll
    for (int ti = 0; ti < 4; ti++)
      #pragma unroll
      for (int tj = 0; tj < 2; tj++){
        acc[ti][tj] = z4;
        #pragma unroll
        for (int kc = 0; kc < 2; kc++)
          acc[ti][tj] = __builtin_amdgcn_mfma_f32_16x16x32_bf16(aw[ti][kc], bx[tj][kc], acc[ti][tj], 0, 0, 0);
      }
    #pragma unroll
    for (int ti = 0; ti < 4; ti++)
      #pragma unroll
      for (int tj = 0; tj < 2; tj++){
        float a0 = bq[ti*16 + lg*4 + 0] - qmv[ti][0];
        float a1 = bq[ti*16 + lg*4 + 1] - qmv[ti][1];
        float a2 = bq[ti*16 + lg*4 + 2] - qmv[ti][2];
        float a3 = bq[ti*16 + lg*4 + 3] - qmv[ti][3];
        float v0 = (acc[ti][tj][0] + a0) * SCL;
        float v1 = (acc[ti][tj][1] + a1) * SCL;
        float v2 = (acc[ti][tj][2] + a2) * SCL;
        float v3 = (acc[ti][tj][3] + a3) * SCL;
        int loc = tj*16 + lr;
        int qd = loc*32 + ti*8 + lg*2;
        sd[pd(qd)]     = cvtpk(v0, v1);
        sd[pd(qd + 1)] = cvtpk(v2, v3);
      }
    #pragma unroll
    for (int c2 = 0; c2 < 4; c2++){
      int s = c2*512 + l*8;
      short8 v = *(const short8*)(stageW + ps(s));
      *(short8*)(Qb + wbase + s) = v;
    }
  }

  // ---------- K -> Kf fragments (+ unary logits) ----------
  {
    short8 aw[4][2];
    #pragma unroll
    for (int ti = 0; ti < 4; ti++)
      #pragma unroll
      for (int kc = 0; kc < 2; kc++){
        const float* wr = wk + (ti*16 + lr)*64 + kc*32 + lg*8;
        short8 t;
        #pragma unroll
        for (int j = 0; j < 8; j++) t[j] = f2bf(wr[j]);
        aw[ti][kc] = t;
      }
    f32x4 acc[4][2];
    #pragma unroll
    for (int ti = 0; ti < 4; ti++)
      #pragma unroll
      for (int tj = 0; tj < 2; tj++){
        acc[ti][tj] = z4;
        #pragma unroll
        for (int kc = 0; kc < 2; kc++)
          acc[ti][tj] = __builtin_amdgcn_mfma_f32_16x16x32_bf16(aw[ti][kc], bx[tj][kc], acc[ti][tj], 0, 0, 0);
      }
    float up[2] = {0.f, 0.f};
    #pragma unroll
    for (int ti = 0; ti < 4; ti++)
      #pragma unroll
      for (int tj = 0; tj < 2; tj++){
        float v0 = acc[ti][tj][0] + bk[ti*16 + lg*4 + 0] - kms[ti*16 + lg*4 + 0];
        float v1 = acc[ti][tj][1] + bk[ti*16 + lg*4 + 1] - kms[ti*16 + lg*4 + 1];
        float v2 = acc[ti][tj][2] + bk[ti*16 + lg*4 + 2] - kms[ti*16 + lg*4 + 2];
        float v3 = acc[ti][tj][3] + bk[ti*16 + lg*4 + 3] - kms[ti*16 + lg*4 + 3];
        up[tj] += qmv[ti][0]*v0 + qmv[ti][1]*v1 + qmv[ti][2]*v2 + qmv[ti][3]*v3;
        // local fragment dword index within this wave's 1024-dword Kf span
        int kd = tj*512 + (ti>>1)*256 + (lr + 16*(2*(ti&1) + (lg>>1)))*4 + (lg&1)*2;
        sd[pd(kd)]     = cvtpk(v0, v1);
        sd[pd(kd + 1)] = cvtpk(v2, v3);
      }
    #pragma unroll
    for (int c2 = 0; c2 < 4; c2++){
      int s = c2*512 + l*8;
      short8 v = *(const short8*)(stageW + ps(s));
      *(short8*)(Kfb + wbase + s) = v;
    }
    #pragma unroll
    for (int tj = 0; tj < 2; tj++){
      float s = up[tj];
      s += __shfl_xor(s, 16);
      s += __shfl_xor(s, 32);
      if (lg == 0) u[(size_t)b*N_PIX + ncol[tj]] = s;
    }
  }

  // ---------- V -> Vf fragments (V^T, pi key order) ----------
  {
    short8 aw[4][2];
    #pragma unroll
    for (int ti = 0; ti < 4; ti++)
      #pragma unroll
      for (int kc = 0; kc < 2; kc++){
        const float* wr = wv + (ti*16 + lr)*64 + kc*32 + lg*8;
        short8 t;
        #pragma unroll
        for (int j = 0; j < 8; j++) t[j] = f2bf(wr[j]);
        aw[ti][kc] = t;
      }
    f32x4 acc[4][2];
    #pragma unroll
    for (int ti = 0; ti < 4; ti++)
      #pragma unroll
      for (int tj = 0; tj < 2; tj++){
        acc[ti][tj] = z4;
        #pragma unroll
        for (int kc = 0; kc < 2; kc++)
          acc[ti][tj] = __builtin_amdgcn_mfma_f32_16x16x32_bf16(aw[ti][kc], bx[tj][kc], acc[ti][tj], 0, 0, 0);
      }
    #pragma unroll
    for (int ti = 0; ti < 4; ti++)
      #pragma unroll
      for (int tj = 0; tj < 2; tj++){
        #pragma unroll
        for (int r = 0; r < 4; r++){
          float v = acc[ti][tj][r] + bv[ti*16 + lg*4 + r];
          int vs0 = ti*512 + ((lr >> 2)*16 + lg*4 + r)*8 + (lr & 3) + 4*tj;
          stageW[ps(vs0)] = f2bf(v);
        }
      }
    #pragma unroll
    for (int c2 = 0; c2 < 4; c2++){
      int s = c2*512 + l*8;
      short8 v = *(const short8*)(stageW + ps(s));
      *(short8*)(Vfb + wbase + s) = v;
    }
  }
}

// ---------------- K2: unary softmax + out_unary (no max pass; u bounded) ----------------
__global__ __launch_bounds__(256) void k_unary(const float* __restrict__ u, const short* __restrict__ Vf,
                                               float* __restrict__ ou){
  int b = blockIdx.x & 7, c = blockIdx.x >> 3;
  int tid = threadIdx.x, w = tid >> 6, l = tid & 63;
  const float* ub = u + (size_t)b * N_PIX;
  const short* Vfb = Vf + (size_t)b * N_PIX * 64;
  int f = c >> 4, c15 = c & 15;
  int g = tid >> 1, h = tid & 1;   // thread covers key-group g, lane-slots 2h,2h+1
  float ps_ = 0.f, vs = 0.f;
  #pragma unroll
  for (int si = 0; si < 2; si++){
    int s = 2*h + si;
    const short8 v = *(const short8*)(Vfb + g*2048 + f*512 + (s*16 + c15)*8);
    #pragma unroll
    for (int j = 0; j < 8; j++){
      int kk = (j < 4) ? (4*s + j) : (16 + 4*s + (j - 4));
      int m = g*32 + kk;
      float p = fexp2(ub[m] * LOG2E);
      ps_ += p;
      vs += p * bf2f(v[j]);
    }
  }
  ps_ = wredSum(ps_); vs = wredSum(vs);
  __shared__ float r1[4], r2[4];
  if (l == 0){ r1[w] = ps_; r2[w] = vs; }
  __syncthreads();
  if (tid == 0) ou[b*64 + c] = (r2[0]+r2[1]+r2[2]+r2[3]) / (r1[0]+r1[1]+r1[2]+r1[3]);
}

// ---------------- K3: flash attention + epilogue (r7 proven body) ----------------
// Fully in-register main loop: swapped QK (S^T), exp2, cvt_pk -> P is directly a
// 16x16x32 B-fragment under pi key order; PV computes O^T = mfma(Vf, P, accT).
// No LDS / no shuffles in the loop. LDS only for the 8-way epilogue combine.
// NOTE: no register prefetch — VGPR budget (84) has no headroom (r8 spilled).
__global__ __launch_bounds__(512, 3) void k_attn(
    const short* __restrict__ Q, const short* __restrict__ Kf, const short* __restrict__ Vf,
    const float* __restrict__ ou, const float* __restrict__ x, float* __restrict__ out)
{
  int blk = blockIdx.x;
  int b  = blk & 7;                 // XCD-affinity: batch b -> XCD b
  int q0 = (blk >> 3) << 6;
  int tid = threadIdx.x;
  int w = tid >> 6, l = tid & 63, lr = l & 15, lg = l >> 4;

  __shared__ short Opart[8][64][66];   // [wave][q][c] bf16 partials
  __shared__ float lW[8][64];          // [wave][q] partial row sums

  const short* Qb  = Q  + (size_t)b * N_PIX * 64;
  const short* Kfb = Kf + (size_t)b * N_PIX * 64;
  const short* Vfb = Vf + (size_t)b * N_PIX * 64;

  // Q as B-fragment (col = q), 4 q-tiles x 2 c-chains
  short8 bq[4][2];
  #pragma unroll
  for (int qt = 0; qt < 4; qt++)
    #pragma unroll
    for (int kc = 0; kc < 2; kc++)
      bq[qt][kc] = *(const short8*)(Qb + (size_t)(q0 + qt*16 + lr)*64 + kc*32 + lg*8);

  f32x4 acc[4][4];      // acc[qt][f] = O^T[c-tile f][q-tile qt] partial
  float rs[4];
  const f32x4 z4 = {0.f, 0.f, 0.f, 0.f};
  #pragma unroll
  for (int qt = 0; qt < 4; qt++){
    rs[qt] = 0.f;
    #pragma unroll
    for (int f = 0; f < 4; f++) acc[qt][f] = z4;
  }

  int kbase = w << 9;   // each of 8 waves owns 512 keys

  for (int it = 0; it < 16; ++it){
    int kb = kbase + (it << 5);
    const short* kp = Kfb + (size_t)kb * 64 + l*8;   // coalesced 1KB frags
    short8 ak00 = *(const short8*)(kp);
    short8 ak01 = *(const short8*)(kp + 512);
    short8 ak10 = *(const short8*)(kp + 1024);
    short8 ak11 = *(const short8*)(kp + 1536);
    const short* vp = Vfb + (size_t)kb * 64 + l*8;
    short8 vf0 = *(const short8*)(vp);
    short8 vf1 = *(const short8*)(vp + 512);
    short8 vf2 = *(const short8*)(vp + 1024);
    short8 vf3 = *(const short8*)(vp + 1536);

    #pragma unroll
    for (int qt = 0; qt < 4; qt++){
      // S^T tiles: D[key][q]
      f32x4 s0 = __builtin_amdgcn_mfma_f32_16x16x32_bf16(ak00, bq[qt][0], z4, 0, 0, 0);
      s0 = __builtin_amdgcn_mfma_f32_16x16x32_bf16(ak01, bq[qt][1], s0, 0, 0, 0);
      f32x4 s1 = __builtin_amdgcn_mfma_f32_16x16x32_bf16(ak10, bq[qt][0], z4, 0, 0, 0);
      s1 = __builtin_amdgcn_mfma_f32_16x16x32_bf16(ak11, bq[qt][1], s1, 0, 0, 0);
      float p00 = fexp2(s0[0]), p01 = fexp2(s0[1]), p02 = fexp2(s0[2]), p03 = fexp2(s0[3]);
      float p10 = fexp2(s1[0]), p11 = fexp2(s1[1]), p12 = fexp2(s1[2]), p13 = fexp2(s1[3]);
      rs[qt] += ((p00 + p01) + (p02 + p03)) + ((p10 + p11) + (p12 + p13));
      union { short8 s; uint32_t u[4]; } pb;
      pb.u[0] = cvtpk(p00, p01);   // pi slots 0,1  (keys 4lg,4lg+1)
      pb.u[1] = cvtpk(p02, p03);   // slots 2,3     (keys 4lg+2,4lg+3)
      pb.u[2] = cvtpk(p10, p11);   // slots 4,5     (keys 16+4lg,16+4lg+1)
      pb.u[3] = cvtpk(p12, p13);   // slots 6,7     (keys 16+4lg+2,+3)
      acc[qt][0] = __builtin_amdgcn_mfma_f32_16x16x32_bf16(vf0, pb.s, acc[qt][0], 0, 0, 0);
      acc[qt][1] = __builtin_amdgcn_mfma_f32_16x16x32_bf16(vf1, pb.s, acc[qt][1], 0, 0, 0);
      acc[qt][2] = __builtin_amdgcn_mfma_f32_16x16x32_bf16(vf2, pb.s, acc[qt][2], 0, 0, 0);
      acc[qt][3] = __builtin_amdgcn_mfma_f32_16x16x32_bf16(vf3, pb.s, acc[qt][3], 0, 0, 0);
    }
  }

  // row sums: reduce over lg groups (q = qt*16 + lr)
  #pragma unroll
  for (int qt = 0; qt < 4; qt++){
    float v = rs[qt];
    v += __shfl_xor(v, 16);
    v += __shfl_xor(v, 32);
    rs[qt] = v;
  }

  if (lg == 0){
    #pragma unroll
    for (int qt = 0; qt < 4; qt++)
      lW[w][qt*16 + lr] = rs[qt];
  }
  // O^T deposit: acc[qt][f][r] = O^T[c = f*16+lg*4+r][q = qt*16+lr]
  #pragma unroll
  for (int qt = 0; qt < 4; qt++)
    #pragma unroll
    for (int f = 0; f < 4; f++)
      #pragma unroll
      for (int r = 0; r < 4; r++)
        Opart[w][qt*16 + lr][f*16 + lg*4 + r] = f2bf(acc[qt][f][r]);
  __syncthreads();

  const float* xb = x + (size_t)b * 64 * N_PIX;
  float* ob = out + (size_t)b * 64 * N_PIX;
  const float* oub = ou + b*64;
  #pragma unroll
  for (int i = 0; i < 8; i++){
    int idx = i*512 + tid;
    int c = idx >> 6, q = idx & 63;
    float os = 0.f, lt = 0.f;
    #pragma unroll
    for (int ww = 0; ww < 8; ww++){
      os += bf2f(Opart[ww][q][c]);
      lt += lW[ww][q];
    }
    size_t gi = (size_t)c * N_PIX + q0 + q;
    ob[gi] = xb[gi] + os / lt + oub[c];
  }
}

extern "C" void kernel_launch(void* const* d_in, const int* in_sizes, int n_in,
                              void* d_out, int out_size, void* d_ws, size_t ws_size,
                              hipStream_t stream)
{
  (void)in_sizes; (void)n_in; (void)out_size; (void)ws_size;
  const float* x  = (const float*)d_in[0];
  const float* wq = (const float*)d_in[1];
  const float* bq = (const float*)d_in[2];
  const float* wk = (const float*)d_in[3];
  const float* bk = (const float*)d_in[4];
  const float* wv = (const float*)d_in[5];
  const float* bv = (const float*)d_in[6];
  float* out = (float*)d_out;

  char* ws = (char*)d_ws;
  short* Q  = (short*)(ws);                 // 4 MiB
  short* Kf = (short*)(ws + 4194304);       // 4 MiB (fragment layout)
  short* Vf = (short*)(ws + 8388608);       // 4 MiB (V^T fragment layout, pi order)
  float* u  = (float*)(ws + 12582912);      // 128 KiB
  float* xm = (float*)(ws + 12713984);
  float* ou = (float*)(ws + 12716032);

  k_xmean<<<dim3(512), dim3(256), 0, stream>>>(x, xm);
  k_qkv<<<dim3(256), dim3(256), 0, stream>>>(x, wq, bq, wk, bk, wv, bv, xm, Q, Kf, Vf, u);
  k_unary<<<dim3(512), dim3(256), 0, stream>>>(u, Vf, ou);
  k_attn<<<dim3(512), dim3(512), 0, stream>>>(Q, Kf, Vf, ou, x, out);
}